// Round 16
// baseline (75.093 us; speedup 1.0000x reference)
//
#include <hip/hip_runtime.h>

typedef short s16x8 __attribute__((ext_vector_type(8)));
typedef float f32x4_t __attribute__((ext_vector_type(4)));

#define VOL 98
#define VPAD 112
#define CH 128
#define NWV 7
#define NTH (NWV * 64)
#define MASKNEG -1e9f

struct Smem {
  unsigned short bufA[VPAD * CH];   // 28672 B: xn (LN out) -> K; stride 256B swz
  unsigned short vt[CH * CH];       // 32768 B: V^T [d][token]; stride 256B swz
  unsigned short pst[NWV][16 * 64]; // 14336 B: per-wave P staging [q16][j64]; stride 128B swz
  unsigned int catbits[27][4];      // 432 B: bit j of catbits[c] => token j has category c
};

__device__ __forceinline__ unsigned short f2bf(float f) {
  unsigned int u = __float_as_uint(f);
  unsigned int r = u + 0x7FFFu + ((u >> 16) & 1u);
  return (unsigned short)(r >> 16);
}
// packed f32x2 -> bf16x2, round-half-up + v_perm_b32 pack (no inline asm; the
// asm cvt_pk variant NaN'd in R3/R4/R7 and is banned; setprio banned per R15).
__device__ __forceinline__ unsigned int pk2(float a, float b) {
#if __has_builtin(__builtin_amdgcn_perm)
  return __builtin_amdgcn_perm(__float_as_uint(b) + 0x8000u,
                               __float_as_uint(a) + 0x8000u,
                               0x07060302u);
#else
  return (unsigned int)f2bf(a) | ((unsigned int)f2bf(b) << 16);
#endif
}
__device__ __forceinline__ int swz(int row, int colEl, int strideB) {
  return (row * strideB + colEl * 2) ^ ((row & 7) << 4);
}
__device__ __forceinline__ s16x8 ldsRd(const unsigned short* buf, int row, int colEl, int strideB) {
  return *(const s16x8*)((const char*)buf + swz(row, colEl, strideB));
}
__device__ __forceinline__ void ldsWr64(unsigned short* buf, int row, int colEl, int strideB,
                                        unsigned int lo, unsigned int hi) {
  unsigned long long v = (unsigned long long)lo | ((unsigned long long)hi << 32);
  *(unsigned long long*)((char*)buf + swz(row, colEl, strideB)) = v;
}
// pst read through the SAME type as the writes (u64): exact aliasing preserves
// write->read order without fences; everything else reorders freely.
__device__ __forceinline__ s16x8 ldsRdP(const unsigned short* buf, int row, int colEl, int strideB) {
  const char* p = (const char*)buf;
  unsigned long long lo = *(const unsigned long long*)(p + swz(row, colEl, strideB));
  unsigned long long hi = *(const unsigned long long*)(p + swz(row, colEl, strideB) + 8);
  union { unsigned long long q[2]; s16x8 v; } u;
  u.q[0] = lo; u.q[1] = hi;
  return u.v;
}
__device__ __forceinline__ void ldsWr128(unsigned short* buf, int row, int colEl, int strideB, uint4 v) {
  *(uint4*)((char*)buf + swz(row, colEl, strideB)) = v;
}
__device__ __forceinline__ s16x8 u4cast(unsigned a, unsigned b, unsigned c, unsigned d) {
  union { uint4 u; s16x8 v; } cv;
  cv.u = make_uint4(a, b, c, d);
  return cv.v;
}
// closed-form per-token helpers (token i in cuboid (nt,nh,nw))
__device__ __forceinline__ int cat_of(int i, int nt, int nh, int nw) {
  int dt = (i >= 49) ? 1 : 0;
  int rem = i - dt * 49;
  int dh = (rem * 37) >> 8;          // rem/7 for rem<49
  int dw = rem - dh * 7;
  int t = nt * 2 + dt, h = nh * 7 + dh, w = nw * 7 + dw;
  int tc = (t < 14) ? 0 : ((t < 15) ? 1 : 2);
  int hc = (h < 49) ? 0 : ((h < 53) ? 1 : 2);
  int wc = (w < 49) ? 0 : ((w < 53) ? 1 : 2);
  return tc * 9 + hc * 3 + wc;
}
__device__ __forceinline__ int gidx_of(int i, int b, int nt, int nh, int nw) {
  int dt = (i >= 49) ? 1 : 0;
  int rem = i - dt * 49;
  int dh = (rem * 37) >> 8;
  int dw = rem - dh * 7;
  int t = nt * 2 + dt, h = nh * 7 + dh, w = nw * 7 + dw;
  int ts = (t + 1) & 15;
  int hs = h + 3; if (hs >= 56) hs -= 56;
  int ws2 = w + 3; if (ws2 >= 56) ws2 -= 56;
  return ((b * 16 + ts) * 56 + hs) * 56 + ws2;
}

// ---------------- weight prepack: fp32 -> bf16 fragments (exact RNE) ----------------
// Q columns (global col < 128) pre-scaled by hd^-0.5 * log2e.
__global__ void prepack_weights(const float* __restrict__ wqkv,
                                const float* __restrict__ wproj,
                                unsigned short* __restrict__ dst) {
  const float QSCALE = (float)(0.17677669529663687 * 1.4426950408889634);
  int lane = threadIdx.x;
  int blk = blockIdx.x;
  if (blk < 96) {
    int ct = blk >> 2, ks = blk & 3;
    int r0 = ks * 32 + ((lane >> 4) << 3);
    int col = ct * 16 + (lane & 15);
    float scl = (ct < 8) ? QSCALE : 1.0f;
    unsigned short* d = dst + (((size_t)(ct * 4 + ks) * 64 + lane) * 8);
#pragma unroll
    for (int j = 0; j < 8; ++j) d[j] = f2bf(wqkv[(size_t)(r0 + j) * 384 + col] * scl);
  } else {
    int bb = blk - 96;
    int ct = bb >> 2, ks = bb & 3;
    int r0 = ks * 32 + ((lane >> 4) << 3);
    int col = ct * 16 + (lane & 15);
    unsigned short* d = dst + 49152 + (((size_t)(ct * 4 + ks) * 64 + lane) * 8);
#pragma unroll
    for (int j = 0; j < 8; ++j) d[j] = f2bf(wproj[(size_t)(r0 + j) * 128 + col]);
  }
}

// ---------------- fused kernel: one block per cuboid, 7 waves, ONE barrier ----------------
__global__ __launch_bounds__(NTH, 4) void fused_cuboid_attn(
    const float* __restrict__ x, const float* __restrict__ gamma,
    const float* __restrict__ beta, const float* __restrict__ bproj,
    const unsigned short* __restrict__ wfrag, float* __restrict__ out) {
  __shared__ Smem s;
  const int tid = threadIdx.x;
  const int lane = tid & 63;
  const int itw = tid >> 6;          // wave id == row-tile id (0..6)
  const int l15 = lane & 15;
  const int lg = lane >> 4;
  const int lg4 = lg * 4;
  const int lg8 = lg * 8;
  const int bid = blockIdx.x;
  const int b = bid >> 9;
  const int n = bid & 511;
  const int nt = n >> 6, nh = (n >> 3) & 7, nw = n & 7;
  // cross-lg relayout constants (used for Q frag and proj O frag)
  const int srcA = (2 * (lg & 1)) * 16 + l15;
  const int srcB = (2 * (lg & 1) + 1) * 16 + l15;
  const bool hiT = (lg >> 1) != 0;

  // phase 1a: issue x loads for this wave's OWN tokens (wave w owns rows
  // 16w..16w+15; group lg handles 4 of them). Wave-own LN makes the whole
  // LN -> xf -> QKV pipeline wave-private (no barriers).
  float4 xv[4][2];
#pragma unroll
  for (int k = 0; k < 4; ++k) {
    int i = itw * 16 + lg * 4 + k;
    if (i < VOL) {
      const float* xp = x + (size_t)gidx_of(i, b, nt, nh, nw) * CH + l15 * 8;
      xv[k][0] = *(const float4*)(xp);
      xv[k][1] = *(const float4*)(xp + 4);
    }
  }

  // phase 1b: LayerNorm into bufA (own rows only)
  {
    const float4 g0 = *(const float4*)(gamma + l15 * 8);
    const float4 g1 = *(const float4*)(gamma + l15 * 8 + 4);
    const float4 be0 = *(const float4*)(beta + l15 * 8);
    const float4 be1 = *(const float4*)(beta + l15 * 8 + 4);
#pragma unroll
    for (int k = 0; k < 4; ++k) {
      int i = itw * 16 + lg * 4 + k;
      if (i < VOL) {
        float4 v0 = xv[k][0];
        float4 v1 = xv[k][1];
        float sum = v0.x + v0.y + v0.z + v0.w + v1.x + v1.y + v1.z + v1.w;
        float ssq = v0.x * v0.x + v0.y * v0.y + v0.z * v0.z + v0.w * v0.w +
                    v1.x * v1.x + v1.y * v1.y + v1.z * v1.z + v1.w * v1.w;
#pragma unroll
        for (int d = 1; d < 16; d <<= 1) {
          sum += __shfl_xor(sum, d);
          ssq += __shfl_xor(ssq, d);
        }
        float mean = sum * (1.0f / 128.0f);
        float var = ssq * (1.0f / 128.0f) - mean * mean;
        float rstd = rsqrtf(var + 1e-5f);
        uint4 pkv;
        pkv.x = pk2((v0.x - mean) * rstd * g0.x + be0.x, (v0.y - mean) * rstd * g0.y + be0.y);
        pkv.y = pk2((v0.z - mean) * rstd * g0.z + be0.z, (v0.w - mean) * rstd * g0.w + be0.w);
        pkv.z = pk2((v1.x - mean) * rstd * g1.x + be1.x, (v1.y - mean) * rstd * g1.y + be1.y);
        pkv.w = pk2((v1.z - mean) * rstd * g1.z + be1.z, (v1.w - mean) * rstd * g1.w + be1.w);
        ldsWr128(s.bufA, i, l15 * 8, 256, pkv);
      }
    }
  }
  // wave 6 (2 LN tokens only): zero its own pad rows 98..111 BEFORE its xf
  // load (wave-private; -> zero Q/K via GEMM on zero input)
  if (itw == 6) {
    uint4 z = make_uint4(0, 0, 0, 0);
    uint4* px = (uint4*)(s.bufA + 98 * CH);
#pragma unroll
    for (int r = 0; r < 4; ++r) {
      int idx = lane + r * 64;
      if (idx < 224) px[idx] = z;
    }
  }
  asm volatile("" ::: "memory");  // order LN uint4* writes vs xf short8* reads (R3/R4 lesson)

  // phase 2: load own-row A-frags, then QKV GEMM (all wave-private writes:
  // K -> own bufA rows, V -> own vt token-cols).
  s16x8 xf[4];
#pragma unroll
  for (int ks = 0; ks < 4; ++ks) xf[ks] = ldsRd(s.bufA, itw * 16 + l15, ks * 32 + lg8, 256);
  asm volatile("" ::: "memory");

  unsigned qp[8][2];
  {
#pragma unroll
    for (int ct = 0; ct < 24; ++ct) {
      const unsigned short* wf = wfrag + ((size_t)ct * 2048 + (size_t)lane * 8);
      s16x8 wv[4];
#pragma unroll
      for (int ks = 0; ks < 4; ++ks) wv[ks] = *(const s16x8*)(wf + ks * 512);
      f32x4_t acc = {0.f, 0.f, 0.f, 0.f};
      if (ct < 16) {
#pragma unroll
        for (int ks = 0; ks < 4; ++ks)
          acc = __builtin_amdgcn_mfma_f32_16x16x32_bf16(wv[ks], xf[ks], acc, 0, 0, 0);
        if (ct < 8) {   // Q pre-scaled in prepack
          qp[ct][0] = pk2(acc[0], acc[1]);
          qp[ct][1] = pk2(acc[2], acc[3]);
        } else {
          ldsWr64(s.bufA, itw * 16 + l15, (ct - 8) * 16 + lg4, 256,
                  pk2(acc[0], acc[1]), pk2(acc[2], acc[3]));
        }
      } else {
#pragma unroll
        for (int ks = 0; ks < 4; ++ks)
          acc = __builtin_amdgcn_mfma_f32_16x16x32_bf16(xf[ks], wv[ks], acc, 0, 0, 0);
        ldsWr64(s.vt, (ct - 16) * 16 + l15, itw * 16 + lg4, 256,
                pk2(acc[0], acc[1]), pk2(acc[2], acc[3]));
      }
    }
  }
  // wave 6 pre-barrier duties (read by all waves only AFTER the barrier):
  // zero vt token-cols 112..127 (PV ks=3 reads them x P=0) and build the
  // category bitmask table closed-form (no cat array, no atomics).
  if (itw == 6) {
    uint4 z = make_uint4(0, 0, 0, 0);
#pragma unroll
    for (int r = 0; r < 2; ++r) {
      int row = lane + r * 64;
      ldsWr128(s.vt, row, 112, 256, z);
      ldsWr128(s.vt, row, 120, 256, z);
    }
    for (int wIdx = lane; wIdx < 108; wIdx += 64) {
      int c = wIdx >> 2, wi = wIdx & 3;
      unsigned bits = 0;
      for (int bbit = 0; bbit < 32; ++bbit) {
        int j = wi * 32 + bbit;
        if (j < VOL && cat_of(j, nt, nh, nw) == c) bits |= (1u << bbit);
      }
      s.catbits[c][wi] = bits;
    }
  }
  __syncthreads();   // THE barrier: K, V^T, catbits complete block-wide

  // phase 3: attention, all 4 heads per wave. S^T = mfma(K, Q, C=mask);
  // lane owns query q = itw*16+l15, keys j = jt*16+lg4+r. O stays in regs.
  // No max subtraction (R11-validated). PV in two half-rounds through the
  // [16][64] staging tile; pst write/read same-type aliased — no fences.
  unsigned oreg[4][4];
  {
    unsigned short* ps = s.pst[itw];
    const int q = itw * 16 + l15;
    const int cq = (q < VOL) ? cat_of(q, nt, nh, nw) : 0;
    const uint4 mwv = *(const uint4*)&s.catbits[cq][0];
    f32x4_t cm[7];
#pragma unroll
    for (int jt = 0; jt < 7; ++jt) {
      unsigned mword = ((jt >> 1) == 0) ? mwv.x : ((jt >> 1) == 1) ? mwv.y
                      : ((jt >> 1) == 2) ? mwv.z : mwv.w;
#pragma unroll
      for (int r = 0; r < 4; ++r)
        cm[jt][r] = ((mword >> ((jt & 1) * 16 + lg4 + r)) & 1u) ? 0.f : MASKNEG;
    }
#pragma unroll
    for (int hh = 0; hh < 4; ++hh) {
      // qa fragment from Q registers via cross-lg shuffles (same l15 column)
      unsigned a0 = __shfl(qp[2 * hh][0], srcA), b0 = __shfl(qp[2 * hh + 1][0], srcA);
      unsigned a1 = __shfl(qp[2 * hh][1], srcA), b1 = __shfl(qp[2 * hh + 1][1], srcA);
      unsigned a2 = __shfl(qp[2 * hh][0], srcB), b2 = __shfl(qp[2 * hh + 1][0], srcB);
      unsigned a3 = __shfl(qp[2 * hh][1], srcB), b3 = __shfl(qp[2 * hh + 1][1], srcB);
      s16x8 qa = u4cast(hiT ? b0 : a0, hiT ? b1 : a1, hiT ? b2 : a2, hiT ? b3 : a3);
      f32x4_t sc[7];
#pragma unroll
      for (int jt = 0; jt < 7; ++jt) {
        s16x8 kb = ldsRd(s.bufA, jt * 16 + l15, hh * 32 + lg8, 256);
        sc[jt] = __builtin_amdgcn_mfma_f32_16x16x32_bf16(kb, qa, cm[jt], 0, 0, 0);
      }
      // p = exp2(s) (log2 domain, scale folded into prepacked Wq); row sum
      float s0 = 0.f, s1 = 0.f, s2 = 0.f, s3 = 0.f;
#pragma unroll
      for (int jt = 0; jt < 7; ++jt) {
        float p0 = exp2f(sc[jt][0]);
        float p1 = exp2f(sc[jt][1]);
        float p2 = exp2f(sc[jt][2]);
        float p3 = exp2f(sc[jt][3]);
        sc[jt][0] = p0; sc[jt][1] = p1; sc[jt][2] = p2; sc[jt][3] = p3;
        s0 += p0; s1 += p1; s2 += p2; s3 += p3;
      }
      float ssum = (s0 + s1) + (s2 + s3);
      ssum += __shfl_xor(ssum, 16);
      ssum += __shfl_xor(ssum, 32);
      float rinv = 1.0f / ssum;
      f32x4_t o0 = {0.f, 0.f, 0.f, 0.f}, o1 = {0.f, 0.f, 0.f, 0.f};
      // half A: keys 0..63 (jt 0..3) -> cols 0..63, then 2 PV chunks
#pragma unroll
      for (int jt = 0; jt < 4; ++jt)
        ldsWr64(ps, l15, jt * 16 + lg4, 128, pk2(sc[jt][0], sc[jt][1]), pk2(sc[jt][2], sc[jt][3]));
#pragma unroll
      for (int ks = 0; ks < 2; ++ks) {
        s16x8 pa = ldsRdP(ps, l15, ks * 32 + lg8, 128);
        s16x8 v0 = ldsRd(s.vt, hh * 32 + l15, ks * 32 + lg8, 256);
        s16x8 v1 = ldsRd(s.vt, hh * 32 + 16 + l15, ks * 32 + lg8, 256);
        o0 = __builtin_amdgcn_mfma_f32_16x16x32_bf16(v0, pa, o0, 0, 0, 0);
        o1 = __builtin_amdgcn_mfma_f32_16x16x32_bf16(v1, pa, o1, 0, 0, 0);
      }
      // half B: keys 64..127 (jt 4..6 + zero pad) -> cols 0..63 (aliases half
      // A's cols -> compiler keeps writes after the reads above)
#pragma unroll
      for (int jt = 4; jt < 7; ++jt)
        ldsWr64(ps, l15, (jt - 4) * 16 + lg4, 128, pk2(sc[jt][0], sc[jt][1]), pk2(sc[jt][2], sc[jt][3]));
      ldsWr64(ps, l15, 48 + lg4, 128, 0u, 0u);
#pragma unroll
      for (int ks = 0; ks < 2; ++ks) {
        s16x8 pa = ldsRdP(ps, l15, ks * 32 + lg8, 128);
        s16x8 v0 = ldsRd(s.vt, hh * 32 + l15, (2 + ks) * 32 + lg8, 256);
        s16x8 v1 = ldsRd(s.vt, hh * 32 + 16 + l15, (2 + ks) * 32 + lg8, 256);
        o0 = __builtin_amdgcn_mfma_f32_16x16x32_bf16(v0, pa, o0, 0, 0, 0);
        o1 = __builtin_amdgcn_mfma_f32_16x16x32_bf16(v1, pa, o1, 0, 0, 0);
      }
      oreg[hh][0] = pk2(o0[0] * rinv, o0[1] * rinv);
      oreg[hh][1] = pk2(o0[2] * rinv, o0[3] * rinv);
      oreg[hh][2] = pk2(o1[0] * rinv, o1[1] * rinv);
      oreg[hh][3] = pk2(o1[2] * rinv, o1[3] * rinv);
    }
  }

  // phase 4: proj A-frags straight from oreg via cross-lg shuffles (no LDS
  // round trip, no barriers; gidx computed closed-form per lane).
  {
    s16x8 of[4];
#pragma unroll
    for (int hh = 0; hh < 4; ++hh) {
      unsigned a0 = __shfl(oreg[hh][0], srcA), a2 = __shfl(oreg[hh][2], srcA);
      unsigned a1 = __shfl(oreg[hh][1], srcA), a3 = __shfl(oreg[hh][3], srcA);
      unsigned c0 = __shfl(oreg[hh][0], srcB), c2 = __shfl(oreg[hh][2], srcB);
      unsigned c1 = __shfl(oreg[hh][1], srcB), c3 = __shfl(oreg[hh][3], srcB);
      of[hh] = u4cast(hiT ? a2 : a0, hiT ? a3 : a1, hiT ? c2 : c0, hiT ? c3 : c1);
    }
    const unsigned short* wp = wfrag + 49152;
    const int row = itw * 16 + l15;
    const bool valid = row < VOL;
    const size_t gbase = valid ? (size_t)gidx_of(row, b, nt, nh, nw) * CH : 0;
#pragma unroll
    for (int ct = 0; ct < 8; ++ct) {
      const unsigned short* wf = wp + ((size_t)ct * 2048 + (size_t)lane * 8);
      float4 b4 = *(const float4*)(bproj + ct * 16 + lg4);
      f32x4_t acc = {b4.x, b4.y, b4.z, b4.w};
#pragma unroll
      for (int ks = 0; ks < 4; ++ks) {
        s16x8 wv = *(const s16x8*)(wf + ks * 512);
        acc = __builtin_amdgcn_mfma_f32_16x16x32_bf16(wv, of[ks], acc, 0, 0, 0);
      }
      if (valid) {
        float4 res;
        res.x = acc[0]; res.y = acc[1]; res.z = acc[2]; res.w = acc[3];
        *(float4*)(out + gbase + ct * 16 + lg4) = res;
      }
    }
  }
}

extern "C" void kernel_launch(void* const* d_in, const int* in_sizes, int n_in,
                              void* d_out, int out_size, void* d_ws, size_t ws_size,
                              hipStream_t stream) {
  const float* x = (const float*)d_in[0];
  const float* gamma = (const float*)d_in[1];
  const float* beta = (const float*)d_in[2];
  const float* wqkv = (const float*)d_in[3];
  const float* wproj = (const float*)d_in[4];
  const float* bproj = (const float*)d_in[5];
  float* out = (float*)d_out;
  unsigned short* wsf = (unsigned short*)d_ws;
  (void)in_sizes; (void)n_in; (void)out_size; (void)ws_size;

  prepack_weights<<<128, 64, 0, stream>>>(wqkv, wproj, wsf);
  fused_cuboid_attn<<<1024, NTH, 0, stream>>>(x, gamma, beta, bproj, wsf, out);
}

// Round 17
// 71.430 us; speedup vs baseline: 1.0513x; 1.0513x over previous
//
#include <hip/hip_runtime.h>

typedef short s16x8 __attribute__((ext_vector_type(8)));
typedef float f32x4_t __attribute__((ext_vector_type(4)));

#define VOL 98
#define VPAD 112
#define CH 128
#define NWV 7
#define NTH (NWV * 64)
#define MASKNEG -1e9f

struct Smem {
  unsigned short bufA[VPAD * CH];   // 28672 B: xn (LN out) -> K; stride 256B swz
  unsigned short vt[CH * CH];       // 32768 B: V^T [d][token]; stride 256B swz
  unsigned short pst[NWV][16 * 64]; // 14336 B: per-wave P staging [q16][j64]; stride 128B swz
  unsigned int catbits[27][4];      // 432 B: bit j of catbits[c] => token j has category c
  int cat[VPAD];
  int gidx[VPAD];
};

__device__ __forceinline__ unsigned short f2bf(float f) {
  unsigned int u = __float_as_uint(f);
  unsigned int r = u + 0x7FFFu + ((u >> 16) & 1u);
  return (unsigned short)(r >> 16);
}
// packed f32x2 -> bf16x2, round-half-up + v_perm_b32 pack (no inline asm; the
// asm cvt_pk variant NaN'd in R3/R4/R7; setprio corrupted results in R15 —
// both banned).
__device__ __forceinline__ unsigned int pk2(float a, float b) {
#if __has_builtin(__builtin_amdgcn_perm)
  return __builtin_amdgcn_perm(__float_as_uint(b) + 0x8000u,
                               __float_as_uint(a) + 0x8000u,
                               0x07060302u);
#else
  return (unsigned int)f2bf(a) | ((unsigned int)f2bf(b) << 16);
#endif
}
__device__ __forceinline__ int swz(int row, int colEl, int strideB) {
  return (row * strideB + colEl * 2) ^ ((row & 7) << 4);
}
__device__ __forceinline__ s16x8 ldsRd(const unsigned short* buf, int row, int colEl, int strideB) {
  return *(const s16x8*)((const char*)buf + swz(row, colEl, strideB));
}
__device__ __forceinline__ void ldsWr64(unsigned short* buf, int row, int colEl, int strideB,
                                        unsigned int lo, unsigned int hi) {
  unsigned long long v = (unsigned long long)lo | ((unsigned long long)hi << 32);
  *(unsigned long long*)((char*)buf + swz(row, colEl, strideB)) = v;
}
// pst read through the SAME type as the writes (u64): exact aliasing preserves
// write->read order without fences; everything else reorders freely.
__device__ __forceinline__ s16x8 ldsRdP(const unsigned short* buf, int row, int colEl, int strideB) {
  const char* p = (const char*)buf;
  unsigned long long lo = *(const unsigned long long*)(p + swz(row, colEl, strideB));
  unsigned long long hi = *(const unsigned long long*)(p + swz(row, colEl, strideB) + 8);
  union { unsigned long long q[2]; s16x8 v; } u;
  u.q[0] = lo; u.q[1] = hi;
  return u.v;
}
__device__ __forceinline__ void ldsWr128(unsigned short* buf, int row, int colEl, int strideB, uint4 v) {
  *(uint4*)((char*)buf + swz(row, colEl, strideB)) = v;
}
__device__ __forceinline__ s16x8 u4cast(unsigned a, unsigned b, unsigned c, unsigned d) {
  union { uint4 u; s16x8 v; } cv;
  cv.u = make_uint4(a, b, c, d);
  return cv.v;
}

// ---------------- weight prepack: fp32 -> bf16 fragments (exact RNE) ----------------
// Q columns (global col < 128) pre-scaled by hd^-0.5 * log2e.
__global__ void prepack_weights(const float* __restrict__ wqkv,
                                const float* __restrict__ wproj,
                                unsigned short* __restrict__ dst) {
  const float QSCALE = (float)(0.17677669529663687 * 1.4426950408889634);
  int lane = threadIdx.x;
  int blk = blockIdx.x;
  if (blk < 96) {
    int ct = blk >> 2, ks = blk & 3;
    int r0 = ks * 32 + ((lane >> 4) << 3);
    int col = ct * 16 + (lane & 15);
    float scl = (ct < 8) ? QSCALE : 1.0f;
    unsigned short* d = dst + (((size_t)(ct * 4 + ks) * 64 + lane) * 8);
#pragma unroll
    for (int j = 0; j < 8; ++j) d[j] = f2bf(wqkv[(size_t)(r0 + j) * 384 + col] * scl);
  } else {
    int bb = blk - 96;
    int ct = bb >> 2, ks = bb & 3;
    int r0 = ks * 32 + ((lane >> 4) << 3);
    int col = ct * 16 + (lane & 15);
    unsigned short* d = dst + 49152 + (((size_t)(ct * 4 + ks) * 64 + lane) * 8);
#pragma unroll
    for (int j = 0; j < 8; ++j) d[j] = f2bf(wproj[(size_t)(r0 + j) * 128 + col]);
  }
}

// ---------------- fused kernel: one block per cuboid, 7 waves ----------------
__global__ __launch_bounds__(NTH, 4) void fused_cuboid_attn(
    const float* __restrict__ x, const float* __restrict__ gamma,
    const float* __restrict__ beta, const float* __restrict__ bproj,
    const unsigned short* __restrict__ wfrag, float* __restrict__ out) {
  __shared__ Smem s;
  const int tid = threadIdx.x;
  const int lane = tid & 63;
  const int itw = tid >> 6;          // wave id == row-tile id (0..6)
  const int l15 = lane & 15;
  const int lg = lane >> 4;
  const int lg4 = lg * 4;
  const int lg8 = lg * 8;
  const int bid = blockIdx.x;
  const int b = bid >> 9;
  const int n = bid & 511;
  const int nt = n >> 6, nh = (n >> 3) & 7, nw = n & 7;
  // cross-lg relayout constants (used for Q frag and proj O frag)
  const int srcA = (2 * (lg & 1)) * 16 + l15;
  const int srcB = (2 * (lg & 1) + 1) * 16 + l15;
  const bool hiT = (lg >> 1) != 0;

  // phase 1a: issue ALL x loads for this thread's LN tokens up front
  const int grp = tid >> 4;
  const int l = tid & 15;
  float4 xv[4][2];
  int giv[4], catv[4];
#pragma unroll
  for (int it2 = 0; it2 < 4; ++it2) {
    int i = grp + it2 * 28;
    if (i < VOL) {
      int dt = (i >= 49) ? 1 : 0;
      int rem = i - dt * 49;
      int dh = (rem * 37) >> 8;
      int dw = rem - dh * 7;
      int t = nt * 2 + dt, h = nh * 7 + dh, w = nw * 7 + dw;
      int ts = (t + 1) & 15;
      int hs = h + 3; if (hs >= 56) hs -= 56;
      int ws2 = w + 3; if (ws2 >= 56) ws2 -= 56;
      int gi = ((b * 16 + ts) * 56 + hs) * 56 + ws2;
      const float* xp = x + (size_t)gi * CH + l * 8;
      xv[it2][0] = *(const float4*)(xp);
      xv[it2][1] = *(const float4*)(xp + 4);
      giv[it2] = gi;
      int tc = (t < 14) ? 0 : ((t < 15) ? 1 : 2);
      int hc = (h < 49) ? 0 : ((h < 53) ? 1 : 2);
      int wc = (w < 49) ? 0 : ((w < 53) ? 1 : 2);
      catv[it2] = tc * 9 + hc * 3 + wc;
    }
  }
  // weight prefetch: ct 0..1 QKV fragments (depend on nothing — issued now so
  // phase 2's first iterations have operands ready; 32 VGPRs, no spill risk)
  s16x8 wpre[2][4];
#pragma unroll
  for (int ct = 0; ct < 2; ++ct)
#pragma unroll
    for (int ks = 0; ks < 4; ++ks)
      wpre[ct][ks] = *(const s16x8*)(wfrag + (size_t)ct * 2048 + (size_t)lane * 8 + ks * 512);

  // phase 0: zero vt (fully: swizzle scatters unwritten token-cols 112..127),
  // bufA pad rows 98..111 (-> zero Q/K/V pads via GEMM), catbits, cat pads.
  {
    uint4 z = make_uint4(0, 0, 0, 0);
    uint4* pv = (uint4*)s.vt;
    for (int i = tid; i < 2048; i += NTH) pv[i] = z;
    if (tid < 224) ((uint4*)(s.bufA + 98 * CH))[tid] = z;
    if (tid < 27) ((uint4*)s.catbits)[tid] = z;
    if (tid >= NTH - (VPAD - VOL)) s.cat[VOL + tid - (NTH - (VPAD - VOL))] = -1;
  }
  __syncthreads();   // barrier 1 of 3

  // phase 1b: LayerNorm into bufA (as xn), one token per 16-lane group + tables
  {
    const float4 g0 = *(const float4*)(gamma + l * 8);
    const float4 g1 = *(const float4*)(gamma + l * 8 + 4);
    const float4 be0 = *(const float4*)(beta + l * 8);
    const float4 be1 = *(const float4*)(beta + l * 8 + 4);
#pragma unroll
    for (int it2 = 0; it2 < 4; ++it2) {
      int i = grp + it2 * 28;
      if (i < VOL) {
        float4 v0 = xv[it2][0];
        float4 v1 = xv[it2][1];
        float sum = v0.x + v0.y + v0.z + v0.w + v1.x + v1.y + v1.z + v1.w;
        float ssq = v0.x * v0.x + v0.y * v0.y + v0.z * v0.z + v0.w * v0.w +
                    v1.x * v1.x + v1.y * v1.y + v1.z * v1.z + v1.w * v1.w;
#pragma unroll
        for (int d = 1; d < 16; d <<= 1) {
          sum += __shfl_xor(sum, d);
          ssq += __shfl_xor(ssq, d);
        }
        float mean = sum * (1.0f / 128.0f);
        float var = ssq * (1.0f / 128.0f) - mean * mean;
        float rstd = rsqrtf(var + 1e-5f);
        uint4 pkv;
        pkv.x = pk2((v0.x - mean) * rstd * g0.x + be0.x, (v0.y - mean) * rstd * g0.y + be0.y);
        pkv.y = pk2((v0.z - mean) * rstd * g0.z + be0.z, (v0.w - mean) * rstd * g0.w + be0.w);
        pkv.z = pk2((v1.x - mean) * rstd * g1.x + be1.x, (v1.y - mean) * rstd * g1.y + be1.y);
        pkv.w = pk2((v1.z - mean) * rstd * g1.z + be1.z, (v1.w - mean) * rstd * g1.w + be1.w);
        ldsWr128(s.bufA, i, l * 8, 256, pkv);
        if (l == 0) {
          s.cat[i] = catv[it2];
          s.gidx[i] = giv[it2];
          atomicOr(&s.catbits[catv[it2]][i >> 5], 1u << (i & 31));
        }
      }
    }
  }
  __syncthreads();   // barrier 2 of 3

  // phase 2: load own-row A-frags (xn), then QKV GEMM — no barrier needed:
  // each wave's K writes touch only its OWN rows (itw*16..+15), the same rows
  // its xf reads. Compile-time fence stops TBAA-based hoisting of the u64*
  // writes above the short8* reads (the R3/R4 lesson).
  s16x8 xf[4];
#pragma unroll
  for (int ks = 0; ks < 4; ++ks) xf[ks] = ldsRd(s.bufA, itw * 16 + l15, ks * 32 + lg8, 256);
  asm volatile("" ::: "memory");

  unsigned qp[8][2];
  {
#pragma unroll
    for (int ct = 0; ct < 24; ++ct) {
      const unsigned short* wf = wfrag + ((size_t)ct * 2048 + (size_t)lane * 8);
      s16x8 wv[4];
#pragma unroll
      for (int ks = 0; ks < 4; ++ks)
        wv[ks] = (ct < 2) ? wpre[ct][ks] : *(const s16x8*)(wf + ks * 512);
      f32x4_t acc = {0.f, 0.f, 0.f, 0.f};
      if (ct < 16) {
#pragma unroll
        for (int ks = 0; ks < 4; ++ks)
          acc = __builtin_amdgcn_mfma_f32_16x16x32_bf16(wv[ks], xf[ks], acc, 0, 0, 0);
        if (ct < 8) {   // Q pre-scaled in prepack
          qp[ct][0] = pk2(acc[0], acc[1]);
          qp[ct][1] = pk2(acc[2], acc[3]);
        } else {
          ldsWr64(s.bufA, itw * 16 + l15, (ct - 8) * 16 + lg4, 256,
                  pk2(acc[0], acc[1]), pk2(acc[2], acc[3]));
        }
      } else {
#pragma unroll
        for (int ks = 0; ks < 4; ++ks)
          acc = __builtin_amdgcn_mfma_f32_16x16x32_bf16(xf[ks], wv[ks], acc, 0, 0, 0);
        ldsWr64(s.vt, (ct - 16) * 16 + l15, itw * 16 + lg4, 256,
                pk2(acc[0], acc[1]), pk2(acc[2], acc[3]));
      }
    }
  }
  __syncthreads();   // barrier 3 of 3: K + V^T complete block-wide

  // phase 3: attention, all 4 heads per wave. S^T = mfma(K, Q, C=mask);
  // lane owns query q = itw*16+l15, keys j = jt*16+lg4+r. O stays in regs.
  // No max subtraction (R11-validated). PV in two half-rounds through the
  // [16][64] staging tile; pst write/read same-type aliased — no fences.
  unsigned oreg[4][4];
  {
    unsigned short* ps = s.pst[itw];
    const int q = itw * 16 + l15;
    int cq = s.cat[q]; if (cq < 0) cq = 0;
    const uint4 mwv = *(const uint4*)&s.catbits[cq][0];
    f32x4_t cm[7];
#pragma unroll
    for (int jt = 0; jt < 7; ++jt) {
      unsigned mword = ((jt >> 1) == 0) ? mwv.x : ((jt >> 1) == 1) ? mwv.y
                      : ((jt >> 1) == 2) ? mwv.z : mwv.w;
#pragma unroll
      for (int r = 0; r < 4; ++r)
        cm[jt][r] = ((mword >> ((jt & 1) * 16 + lg4 + r)) & 1u) ? 0.f : MASKNEG;
    }
#pragma unroll
    for (int hh = 0; hh < 4; ++hh) {
      // qa fragment from Q registers via cross-lg shuffles (same l15 column)
      unsigned a0 = __shfl(qp[2 * hh][0], srcA), b0 = __shfl(qp[2 * hh + 1][0], srcA);
      unsigned a1 = __shfl(qp[2 * hh][1], srcA), b1 = __shfl(qp[2 * hh + 1][1], srcA);
      unsigned a2 = __shfl(qp[2 * hh][0], srcB), b2 = __shfl(qp[2 * hh + 1][0], srcB);
      unsigned a3 = __shfl(qp[2 * hh][1], srcB), b3 = __shfl(qp[2 * hh + 1][1], srcB);
      s16x8 qa = u4cast(hiT ? b0 : a0, hiT ? b1 : a1, hiT ? b2 : a2, hiT ? b3 : a3);
      f32x4_t sc[7];
#pragma unroll
      for (int jt = 0; jt < 7; ++jt) {
        s16x8 kb = ldsRd(s.bufA, jt * 16 + l15, hh * 32 + lg8, 256);
        sc[jt] = __builtin_amdgcn_mfma_f32_16x16x32_bf16(kb, qa, cm[jt], 0, 0, 0);
      }
      // p = exp2(s) (log2 domain, scale folded into prepacked Wq); row sum
      float s0 = 0.f, s1 = 0.f, s2 = 0.f, s3 = 0.f;
#pragma unroll
      for (int jt = 0; jt < 7; ++jt) {
        float p0 = exp2f(sc[jt][0]);
        float p1 = exp2f(sc[jt][1]);
        float p2 = exp2f(sc[jt][2]);
        float p3 = exp2f(sc[jt][3]);
        sc[jt][0] = p0; sc[jt][1] = p1; sc[jt][2] = p2; sc[jt][3] = p3;
        s0 += p0; s1 += p1; s2 += p2; s3 += p3;
      }
      float ssum = (s0 + s1) + (s2 + s3);
      ssum += __shfl_xor(ssum, 16);
      ssum += __shfl_xor(ssum, 32);
      float rinv = 1.0f / ssum;
      f32x4_t o0 = {0.f, 0.f, 0.f, 0.f}, o1 = {0.f, 0.f, 0.f, 0.f};
      // half A: keys 0..63 (jt 0..3) -> cols 0..63, then 2 PV chunks
#pragma unroll
      for (int jt = 0; jt < 4; ++jt)
        ldsWr64(ps, l15, jt * 16 + lg4, 128, pk2(sc[jt][0], sc[jt][1]), pk2(sc[jt][2], sc[jt][3]));
#pragma unroll
      for (int ks = 0; ks < 2; ++ks) {
        s16x8 pa = ldsRdP(ps, l15, ks * 32 + lg8, 128);
        s16x8 v0 = ldsRd(s.vt, hh * 32 + l15, ks * 32 + lg8, 256);
        s16x8 v1 = ldsRd(s.vt, hh * 32 + 16 + l15, ks * 32 + lg8, 256);
        o0 = __builtin_amdgcn_mfma_f32_16x16x32_bf16(v0, pa, o0, 0, 0, 0);
        o1 = __builtin_amdgcn_mfma_f32_16x16x32_bf16(v1, pa, o1, 0, 0, 0);
      }
      // half B: keys 64..127 (jt 4..6 + zero pad) -> cols 0..63 (aliases half
      // A's cols -> compiler keeps writes after the reads above)
#pragma unroll
      for (int jt = 4; jt < 7; ++jt)
        ldsWr64(ps, l15, (jt - 4) * 16 + lg4, 128, pk2(sc[jt][0], sc[jt][1]), pk2(sc[jt][2], sc[jt][3]));
      ldsWr64(ps, l15, 48 + lg4, 128, 0u, 0u);
#pragma unroll
      for (int ks = 0; ks < 2; ++ks) {
        s16x8 pa = ldsRdP(ps, l15, ks * 32 + lg8, 128);
        s16x8 v0 = ldsRd(s.vt, hh * 32 + l15, (2 + ks) * 32 + lg8, 256);
        s16x8 v1 = ldsRd(s.vt, hh * 32 + 16 + l15, (2 + ks) * 32 + lg8, 256);
        o0 = __builtin_amdgcn_mfma_f32_16x16x32_bf16(v0, pa, o0, 0, 0, 0);
        o1 = __builtin_amdgcn_mfma_f32_16x16x32_bf16(v1, pa, o1, 0, 0, 0);
      }
      oreg[hh][0] = pk2(o0[0] * rinv, o0[1] * rinv);
      oreg[hh][1] = pk2(o0[2] * rinv, o0[3] * rinv);
      oreg[hh][2] = pk2(o1[0] * rinv, o1[1] * rinv);
      oreg[hh][3] = pk2(o1[2] * rinv, o1[3] * rinv);
    }
  }

  // phase 4: proj A-frags straight from oreg via cross-lg shuffles (no LDS
  // round trip, no barriers; gidx was written before barrier 2).
  {
    s16x8 of[4];
#pragma unroll
    for (int hh = 0; hh < 4; ++hh) {
      unsigned a0 = __shfl(oreg[hh][0], srcA), a2 = __shfl(oreg[hh][2], srcA);
      unsigned a1 = __shfl(oreg[hh][1], srcA), a3 = __shfl(oreg[hh][3], srcA);
      unsigned c0 = __shfl(oreg[hh][0], srcB), c2 = __shfl(oreg[hh][2], srcB);
      unsigned c1 = __shfl(oreg[hh][1], srcB), c3 = __shfl(oreg[hh][3], srcB);
      of[hh] = u4cast(hiT ? a2 : a0, hiT ? a3 : a1, hiT ? c2 : c0, hiT ? c3 : c1);
    }
    const unsigned short* wp = wfrag + 49152;
    const int row = itw * 16 + l15;
    const bool valid = row < VOL;
    const size_t gbase = valid ? (size_t)s.gidx[row] * CH : 0;
#pragma unroll
    for (int ct = 0; ct < 8; ++ct) {
      const unsigned short* wf = wp + ((size_t)ct * 2048 + (size_t)lane * 8);
      float4 b4 = *(const float4*)(bproj + ct * 16 + lg4);
      f32x4_t acc = {b4.x, b4.y, b4.z, b4.w};
#pragma unroll
      for (int ks = 0; ks < 4; ++ks) {
        s16x8 wv = *(const s16x8*)(wf + ks * 512);
        acc = __builtin_amdgcn_mfma_f32_16x16x32_bf16(wv, of[ks], acc, 0, 0, 0);
      }
      if (valid) {
        float4 res;
        res.x = acc[0]; res.y = acc[1]; res.z = acc[2]; res.w = acc[3];
        *(float4*)(out + gbase + ct * 16 + lg4) = res;
      }
    }
  }
}

extern "C" void kernel_launch(void* const* d_in, const int* in_sizes, int n_in,
                              void* d_out, int out_size, void* d_ws, size_t ws_size,
                              hipStream_t stream) {
  const float* x = (const float*)d_in[0];
  const float* gamma = (const float*)d_in[1];
  const float* beta = (const float*)d_in[2];
  const float* wqkv = (const float*)d_in[3];
  const float* wproj = (const float*)d_in[4];
  const float* bproj = (const float*)d_in[5];
  float* out = (float*)d_out;
  unsigned short* wsf = (unsigned short*)d_ws;
  (void)in_sizes; (void)n_in; (void)out_size; (void)ws_size;

  prepack_weights<<<128, 64, 0, stream>>>(wqkv, wproj, wsf);
  fused_cuboid_attn<<<1024, NTH, 0, stream>>>(x, gamma, beta, bproj, wsf, out);
}

// Round 18
// 69.808 us; speedup vs baseline: 1.0757x; 1.0232x over previous
//
#include <hip/hip_runtime.h>

typedef short s16x8 __attribute__((ext_vector_type(8)));
typedef float f32x4_t __attribute__((ext_vector_type(4)));

#define VOL 98
#define VPAD 112
#define CH 128
#define NWV 7
#define NTH (NWV * 64)
#define MASKNEG -1e9f

struct Smem {
  unsigned short bufA[VPAD * CH];   // 28672 B: xn (LN out) -> K; stride 256B swz
  unsigned short vt[CH * CH];       // 32768 B: V^T [d][token]; stride 256B swz
  unsigned short pst[NWV][16 * 64]; // 14336 B: per-wave P staging [q16][j64]; stride 128B swz
  unsigned int catbits[27][4];      // 432 B: bit j of catbits[c] => token j has category c
  int cat[VPAD];
  int gidx[VPAD];
};

__device__ __forceinline__ unsigned short f2bf(float f) {
  unsigned int u = __float_as_uint(f);
  unsigned int r = u + 0x7FFFu + ((u >> 16) & 1u);
  return (unsigned short)(r >> 16);
}
// packed f32x2 -> bf16x2, round-half-up + v_perm_b32 pack (no inline asm; the
// asm cvt_pk variant NaN'd in R3/R4/R7; setprio corrupted results in R15 —
// both banned).
__device__ __forceinline__ unsigned int pk2(float a, float b) {
#if __has_builtin(__builtin_amdgcn_perm)
  return __builtin_amdgcn_perm(__float_as_uint(b) + 0x8000u,
                               __float_as_uint(a) + 0x8000u,
                               0x07060302u);
#else
  return (unsigned int)f2bf(a) | ((unsigned int)f2bf(b) << 16);
#endif
}
__device__ __forceinline__ int swz(int row, int colEl, int strideB) {
  return (row * strideB + colEl * 2) ^ ((row & 7) << 4);
}
__device__ __forceinline__ s16x8 ldsRd(const unsigned short* buf, int row, int colEl, int strideB) {
  return *(const s16x8*)((const char*)buf + swz(row, colEl, strideB));
}
__device__ __forceinline__ void ldsWr64(unsigned short* buf, int row, int colEl, int strideB,
                                        unsigned int lo, unsigned int hi) {
  unsigned long long v = (unsigned long long)lo | ((unsigned long long)hi << 32);
  *(unsigned long long*)((char*)buf + swz(row, colEl, strideB)) = v;
}
// pst read through the SAME type as the writes (u64): exact aliasing preserves
// write->read order without fences; everything else reorders freely.
__device__ __forceinline__ s16x8 ldsRdP(const unsigned short* buf, int row, int colEl, int strideB) {
  const char* p = (const char*)buf;
  unsigned long long lo = *(const unsigned long long*)(p + swz(row, colEl, strideB));
  unsigned long long hi = *(const unsigned long long*)(p + swz(row, colEl, strideB) + 8);
  union { unsigned long long q[2]; s16x8 v; } u;
  u.q[0] = lo; u.q[1] = hi;
  return u.v;
}
__device__ __forceinline__ void ldsWr128(unsigned short* buf, int row, int colEl, int strideB, uint4 v) {
  *(uint4*)((char*)buf + swz(row, colEl, strideB)) = v;
}
__device__ __forceinline__ s16x8 u4cast(unsigned a, unsigned b, unsigned c, unsigned d) {
  union { uint4 u; s16x8 v; } cv;
  cv.u = make_uint4(a, b, c, d);
  return cv.v;
}

// ---------------- weight prepack: fp32 -> bf16 fragments (exact RNE) ----------------
// Q columns (global col < 128) pre-scaled by hd^-0.5 * log2e.
__global__ void prepack_weights(const float* __restrict__ wqkv,
                                const float* __restrict__ wproj,
                                unsigned short* __restrict__ dst) {
  const float QSCALE = (float)(0.17677669529663687 * 1.4426950408889634);
  int lane = threadIdx.x;
  int blk = blockIdx.x;
  if (blk < 96) {
    int ct = blk >> 2, ks = blk & 3;
    int r0 = ks * 32 + ((lane >> 4) << 3);
    int col = ct * 16 + (lane & 15);
    float scl = (ct < 8) ? QSCALE : 1.0f;
    unsigned short* d = dst + (((size_t)(ct * 4 + ks) * 64 + lane) * 8);
#pragma unroll
    for (int j = 0; j < 8; ++j) d[j] = f2bf(wqkv[(size_t)(r0 + j) * 384 + col] * scl);
  } else {
    int bb = blk - 96;
    int ct = bb >> 2, ks = bb & 3;
    int r0 = ks * 32 + ((lane >> 4) << 3);
    int col = ct * 16 + (lane & 15);
    unsigned short* d = dst + 49152 + (((size_t)(ct * 4 + ks) * 64 + lane) * 8);
#pragma unroll
    for (int j = 0; j < 8; ++j) d[j] = f2bf(wproj[(size_t)(r0 + j) * 128 + col]);
  }
}

// ---------------- fused kernel: one block per cuboid, 7 waves ----------------
__global__ __launch_bounds__(NTH, 4) void fused_cuboid_attn(
    const float* __restrict__ x, const float* __restrict__ gamma,
    const float* __restrict__ beta, const float* __restrict__ bproj,
    const unsigned short* __restrict__ wfrag, float* __restrict__ out) {
  __shared__ Smem s;
  const int tid = threadIdx.x;
  const int lane = tid & 63;
  const int itw = tid >> 6;          // wave id == row-tile id (0..6)
  const int l15 = lane & 15;
  const int lg = lane >> 4;
  const int lg4 = lg * 4;
  const int lg8 = lg * 8;
  const int bid = blockIdx.x;
  const int b = bid >> 9;
  const int n = bid & 511;
  const int nt = n >> 6, nh = (n >> 3) & 7, nw = n & 7;
  // cross-lg relayout constants (used for Q frag and proj O frag)
  const int srcA = (2 * (lg & 1)) * 16 + l15;
  const int srcB = (2 * (lg & 1) + 1) * 16 + l15;
  const bool hiT = (lg >> 1) != 0;

  // phase 1a: issue ALL x loads for this thread's LN tokens up front
  const int grp = tid >> 4;
  const int l = tid & 15;
  float4 xv[4][2];
  int giv[4], catv[4];
#pragma unroll
  for (int it2 = 0; it2 < 4; ++it2) {
    int i = grp + it2 * 28;
    if (i < VOL) {
      int dt = (i >= 49) ? 1 : 0;
      int rem = i - dt * 49;
      int dh = (rem * 37) >> 8;
      int dw = rem - dh * 7;
      int t = nt * 2 + dt, h = nh * 7 + dh, w = nw * 7 + dw;
      int ts = (t + 1) & 15;
      int hs = h + 3; if (hs >= 56) hs -= 56;
      int ws2 = w + 3; if (ws2 >= 56) ws2 -= 56;
      int gi = ((b * 16 + ts) * 56 + hs) * 56 + ws2;
      const float* xp = x + (size_t)gi * CH + l * 8;
      xv[it2][0] = *(const float4*)(xp);
      xv[it2][1] = *(const float4*)(xp + 4);
      giv[it2] = gi;
      int tc = (t < 14) ? 0 : ((t < 15) ? 1 : 2);
      int hc = (h < 49) ? 0 : ((h < 53) ? 1 : 2);
      int wc = (w < 49) ? 0 : ((w < 53) ? 1 : 2);
      catv[it2] = tc * 9 + hc * 3 + wc;
    }
  }

  // phase 0: zero vt (fully: swizzle scatters unwritten token-cols 112..127),
  // bufA pad rows 98..111 (-> zero Q/K/V pads via GEMM), catbits, cat pads.
  {
    uint4 z = make_uint4(0, 0, 0, 0);
    uint4* pv = (uint4*)s.vt;
    for (int i = tid; i < 2048; i += NTH) pv[i] = z;
    if (tid < 224) ((uint4*)(s.bufA + 98 * CH))[tid] = z;
    if (tid < 27) ((uint4*)s.catbits)[tid] = z;
    if (tid >= NTH - (VPAD - VOL)) s.cat[VOL + tid - (NTH - (VPAD - VOL))] = -1;
  }
  __syncthreads();   // barrier 1 of 3

  // phase 1b: LayerNorm into bufA (as xn), one token per 16-lane group + tables
  {
    const float4 g0 = *(const float4*)(gamma + l * 8);
    const float4 g1 = *(const float4*)(gamma + l * 8 + 4);
    const float4 be0 = *(const float4*)(beta + l * 8);
    const float4 be1 = *(const float4*)(beta + l * 8 + 4);
#pragma unroll
    for (int it2 = 0; it2 < 4; ++it2) {
      int i = grp + it2 * 28;
      if (i < VOL) {
        float4 v0 = xv[it2][0];
        float4 v1 = xv[it2][1];
        float sum = v0.x + v0.y + v0.z + v0.w + v1.x + v1.y + v1.z + v1.w;
        float ssq = v0.x * v0.x + v0.y * v0.y + v0.z * v0.z + v0.w * v0.w +
                    v1.x * v1.x + v1.y * v1.y + v1.z * v1.z + v1.w * v1.w;
#pragma unroll
        for (int d = 1; d < 16; d <<= 1) {
          sum += __shfl_xor(sum, d);
          ssq += __shfl_xor(ssq, d);
        }
        float mean = sum * (1.0f / 128.0f);
        float var = ssq * (1.0f / 128.0f) - mean * mean;
        float rstd = rsqrtf(var + 1e-5f);
        uint4 pkv;
        pkv.x = pk2((v0.x - mean) * rstd * g0.x + be0.x, (v0.y - mean) * rstd * g0.y + be0.y);
        pkv.y = pk2((v0.z - mean) * rstd * g0.z + be0.z, (v0.w - mean) * rstd * g0.w + be0.w);
        pkv.z = pk2((v1.x - mean) * rstd * g1.x + be1.x, (v1.y - mean) * rstd * g1.y + be1.y);
        pkv.w = pk2((v1.z - mean) * rstd * g1.z + be1.z, (v1.w - mean) * rstd * g1.w + be1.w);
        ldsWr128(s.bufA, i, l * 8, 256, pkv);
        if (l == 0) {
          s.cat[i] = catv[it2];
          s.gidx[i] = giv[it2];
          atomicOr(&s.catbits[catv[it2]][i >> 5], 1u << (i & 31));
        }
      }
    }
  }
  __syncthreads();   // barrier 2 of 3

  // phase 2: load own-row A-frags (xn), then QKV GEMM — no barrier needed:
  // each wave's K writes touch only its OWN rows (itw*16..+15), the same rows
  // its xf reads. Compile-time fence stops TBAA-based hoisting of the u64*
  // writes above the short8* reads (the R3/R4 lesson).
  s16x8 xf[4];
#pragma unroll
  for (int ks = 0; ks < 4; ++ks) xf[ks] = ldsRd(s.bufA, itw * 16 + l15, ks * 32 + lg8, 256);
  asm volatile("" ::: "memory");

  unsigned qp[8][2];
  {
#pragma unroll
    for (int ct = 0; ct < 24; ++ct) {
      const unsigned short* wf = wfrag + ((size_t)ct * 2048 + (size_t)lane * 8);
      s16x8 wv[4];
#pragma unroll
      for (int ks = 0; ks < 4; ++ks) wv[ks] = *(const s16x8*)(wf + ks * 512);
      f32x4_t acc = {0.f, 0.f, 0.f, 0.f};
      if (ct < 16) {
#pragma unroll
        for (int ks = 0; ks < 4; ++ks)
          acc = __builtin_amdgcn_mfma_f32_16x16x32_bf16(wv[ks], xf[ks], acc, 0, 0, 0);
        if (ct < 8) {   // Q pre-scaled in prepack
          qp[ct][0] = pk2(acc[0], acc[1]);
          qp[ct][1] = pk2(acc[2], acc[3]);
        } else {
          ldsWr64(s.bufA, itw * 16 + l15, (ct - 8) * 16 + lg4, 256,
                  pk2(acc[0], acc[1]), pk2(acc[2], acc[3]));
        }
      } else {
#pragma unroll
        for (int ks = 0; ks < 4; ++ks)
          acc = __builtin_amdgcn_mfma_f32_16x16x32_bf16(xf[ks], wv[ks], acc, 0, 0, 0);
        ldsWr64(s.vt, (ct - 16) * 16 + l15, itw * 16 + lg4, 256,
                pk2(acc[0], acc[1]), pk2(acc[2], acc[3]));
      }
    }
  }
  __syncthreads();   // barrier 3 of 3: K + V^T complete block-wide

  // phase 3: attention, all 4 heads per wave. S^T = mfma(K, Q, C=mask);
  // lane owns query q = itw*16+l15, keys j = jt*16+lg4+r. O stays in regs.
  // No max subtraction (R11-validated). PV in two half-rounds through the
  // [16][64] staging tile; pst write/read same-type aliased — no fences.
  unsigned oreg[4][4];
  {
    unsigned short* ps = s.pst[itw];
    const int q = itw * 16 + l15;
    int cq = s.cat[q]; if (cq < 0) cq = 0;
    const uint4 mwv = *(const uint4*)&s.catbits[cq][0];
    f32x4_t cm[7];
#pragma unroll
    for (int jt = 0; jt < 7; ++jt) {
      unsigned mword = ((jt >> 1) == 0) ? mwv.x : ((jt >> 1) == 1) ? mwv.y
                      : ((jt >> 1) == 2) ? mwv.z : mwv.w;
#pragma unroll
      for (int r = 0; r < 4; ++r)
        cm[jt][r] = ((mword >> ((jt & 1) * 16 + lg4 + r)) & 1u) ? 0.f : MASKNEG;
    }
#pragma unroll
    for (int hh = 0; hh < 4; ++hh) {
      // qa fragment from Q registers via cross-lg shuffles (same l15 column)
      unsigned a0 = __shfl(qp[2 * hh][0], srcA), b0 = __shfl(qp[2 * hh + 1][0], srcA);
      unsigned a1 = __shfl(qp[2 * hh][1], srcA), b1 = __shfl(qp[2 * hh + 1][1], srcA);
      unsigned a2 = __shfl(qp[2 * hh][0], srcB), b2 = __shfl(qp[2 * hh + 1][0], srcB);
      unsigned a3 = __shfl(qp[2 * hh][1], srcB), b3 = __shfl(qp[2 * hh + 1][1], srcB);
      s16x8 qa = u4cast(hiT ? b0 : a0, hiT ? b1 : a1, hiT ? b2 : a2, hiT ? b3 : a3);
      f32x4_t sc[7];
#pragma unroll
      for (int jt = 0; jt < 7; ++jt) {
        s16x8 kb = ldsRd(s.bufA, jt * 16 + l15, hh * 32 + lg8, 256);
        sc[jt] = __builtin_amdgcn_mfma_f32_16x16x32_bf16(kb, qa, cm[jt], 0, 0, 0);
      }
      // p = exp2(s) (log2 domain, scale folded into prepacked Wq); row sum
      float s0 = 0.f, s1 = 0.f, s2 = 0.f, s3 = 0.f;
#pragma unroll
      for (int jt = 0; jt < 7; ++jt) {
        float p0 = exp2f(sc[jt][0]);
        float p1 = exp2f(sc[jt][1]);
        float p2 = exp2f(sc[jt][2]);
        float p3 = exp2f(sc[jt][3]);
        sc[jt][0] = p0; sc[jt][1] = p1; sc[jt][2] = p2; sc[jt][3] = p3;
        s0 += p0; s1 += p1; s2 += p2; s3 += p3;
      }
      float ssum = (s0 + s1) + (s2 + s3);
      ssum += __shfl_xor(ssum, 16);
      ssum += __shfl_xor(ssum, 32);
      float rinv = 1.0f / ssum;
      f32x4_t o0 = {0.f, 0.f, 0.f, 0.f}, o1 = {0.f, 0.f, 0.f, 0.f};
      // half A: keys 0..63 (jt 0..3) -> cols 0..63, then 2 PV chunks
#pragma unroll
      for (int jt = 0; jt < 4; ++jt)
        ldsWr64(ps, l15, jt * 16 + lg4, 128, pk2(sc[jt][0], sc[jt][1]), pk2(sc[jt][2], sc[jt][3]));
#pragma unroll
      for (int ks = 0; ks < 2; ++ks) {
        s16x8 pa = ldsRdP(ps, l15, ks * 32 + lg8, 128);
        s16x8 v0 = ldsRd(s.vt, hh * 32 + l15, ks * 32 + lg8, 256);
        s16x8 v1 = ldsRd(s.vt, hh * 32 + 16 + l15, ks * 32 + lg8, 256);
        o0 = __builtin_amdgcn_mfma_f32_16x16x32_bf16(v0, pa, o0, 0, 0, 0);
        o1 = __builtin_amdgcn_mfma_f32_16x16x32_bf16(v1, pa, o1, 0, 0, 0);
      }
      // half B: keys 64..127 (jt 4..6 + zero pad) -> cols 0..63 (aliases half
      // A's cols -> compiler keeps writes after the reads above)
#pragma unroll
      for (int jt = 4; jt < 7; ++jt)
        ldsWr64(ps, l15, (jt - 4) * 16 + lg4, 128, pk2(sc[jt][0], sc[jt][1]), pk2(sc[jt][2], sc[jt][3]));
      ldsWr64(ps, l15, 48 + lg4, 128, 0u, 0u);
#pragma unroll
      for (int ks = 0; ks < 2; ++ks) {
        s16x8 pa = ldsRdP(ps, l15, ks * 32 + lg8, 128);
        s16x8 v0 = ldsRd(s.vt, hh * 32 + l15, (2 + ks) * 32 + lg8, 256);
        s16x8 v1 = ldsRd(s.vt, hh * 32 + 16 + l15, (2 + ks) * 32 + lg8, 256);
        o0 = __builtin_amdgcn_mfma_f32_16x16x32_bf16(v0, pa, o0, 0, 0, 0);
        o1 = __builtin_amdgcn_mfma_f32_16x16x32_bf16(v1, pa, o1, 0, 0, 0);
      }
      oreg[hh][0] = pk2(o0[0] * rinv, o0[1] * rinv);
      oreg[hh][1] = pk2(o0[2] * rinv, o0[3] * rinv);
      oreg[hh][2] = pk2(o1[0] * rinv, o1[1] * rinv);
      oreg[hh][3] = pk2(o1[2] * rinv, o1[3] * rinv);
    }
  }

  // phase 4: proj A-frags straight from oreg via cross-lg shuffles (no LDS
  // round trip, no barriers; gidx was written before barrier 2).
  {
    s16x8 of[4];
#pragma unroll
    for (int hh = 0; hh < 4; ++hh) {
      unsigned a0 = __shfl(oreg[hh][0], srcA), a2 = __shfl(oreg[hh][2], srcA);
      unsigned a1 = __shfl(oreg[hh][1], srcA), a3 = __shfl(oreg[hh][3], srcA);
      unsigned c0 = __shfl(oreg[hh][0], srcB), c2 = __shfl(oreg[hh][2], srcB);
      unsigned c1 = __shfl(oreg[hh][1], srcB), c3 = __shfl(oreg[hh][3], srcB);
      of[hh] = u4cast(hiT ? a2 : a0, hiT ? a3 : a1, hiT ? c2 : c0, hiT ? c3 : c1);
    }
    const unsigned short* wp = wfrag + 49152;
    const int row = itw * 16 + l15;
    const bool valid = row < VOL;
    const size_t gbase = valid ? (size_t)s.gidx[row] * CH : 0;
#pragma unroll
    for (int ct = 0; ct < 8; ++ct) {
      const unsigned short* wf = wp + ((size_t)ct * 2048 + (size_t)lane * 8);
      float4 b4 = *(const float4*)(bproj + ct * 16 + lg4);
      f32x4_t acc = {b4.x, b4.y, b4.z, b4.w};
#pragma unroll
      for (int ks = 0; ks < 4; ++ks) {
        s16x8 wv = *(const s16x8*)(wf + ks * 512);
        acc = __builtin_amdgcn_mfma_f32_16x16x32_bf16(wv, of[ks], acc, 0, 0, 0);
      }
      if (valid) {
        float4 res;
        res.x = acc[0]; res.y = acc[1]; res.z = acc[2]; res.w = acc[3];
        *(float4*)(out + gbase + ct * 16 + lg4) = res;
      }
    }
  }
}

extern "C" void kernel_launch(void* const* d_in, const int* in_sizes, int n_in,
                              void* d_out, int out_size, void* d_ws, size_t ws_size,
                              hipStream_t stream) {
  const float* x = (const float*)d_in[0];
  const float* gamma = (const float*)d_in[1];
  const float* beta = (const float*)d_in[2];
  const float* wqkv = (const float*)d_in[3];
  const float* wproj = (const float*)d_in[4];
  const float* bproj = (const float*)d_in[5];
  float* out = (float*)d_out;
  unsigned short* wsf = (unsigned short*)d_ws;
  (void)in_sizes; (void)n_in; (void)out_size; (void)ws_size;

  prepack_weights<<<128, 64, 0, stream>>>(wqkv, wproj, wsf);
  fused_cuboid_attn<<<1024, NTH, 0, stream>>>(x, gamma, beta, bproj, wsf, out);
}

// Round 19
// 67.406 us; speedup vs baseline: 1.1141x; 1.0356x over previous
//
#include <hip/hip_runtime.h>

typedef short s16x8 __attribute__((ext_vector_type(8)));
typedef float f32x4_t __attribute__((ext_vector_type(4)));

#define VOL 98
#define VPAD 112
#define CH 128
#define NWV 7
#define NTH (NWV * 64)
#define MASKNEG -1e9f

struct Smem {
  unsigned short bufA[VPAD * CH];   // 28672 B: xn (LN out) -> K; stride 256B swz
  unsigned short vt[CH * CH];       // 32768 B: V^T [d][token]; stride 256B swz
  unsigned short pst[NWV][16 * 64]; // 14336 B: per-wave P staging [q16][j64]; stride 128B swz
};

__device__ __forceinline__ unsigned short f2bf(float f) {
  unsigned int u = __float_as_uint(f);
  unsigned int r = u + 0x7FFFu + ((u >> 16) & 1u);
  return (unsigned short)(r >> 16);
}
// packed f32x2 -> bf16x2, round-half-up + v_perm_b32 (no inline asm; asm
// cvt_pk NaN'd in R3/R4/R7, setprio corrupted in R15 — both banned).
__device__ __forceinline__ unsigned int pk2(float a, float b) {
#if __has_builtin(__builtin_amdgcn_perm)
  return __builtin_amdgcn_perm(__float_as_uint(b) + 0x8000u,
                               __float_as_uint(a) + 0x8000u,
                               0x07060302u);
#else
  return (unsigned int)f2bf(a) | ((unsigned int)f2bf(b) << 16);
#endif
}
__device__ __forceinline__ int swz(int row, int colEl, int strideB) {
  return (row * strideB + colEl * 2) ^ ((row & 7) << 4);
}
__device__ __forceinline__ s16x8 ldsRd(const unsigned short* buf, int row, int colEl, int strideB) {
  return *(const s16x8*)((const char*)buf + swz(row, colEl, strideB));
}
__device__ __forceinline__ void ldsWr64(unsigned short* buf, int row, int colEl, int strideB,
                                        unsigned int lo, unsigned int hi) {
  unsigned long long v = (unsigned long long)lo | ((unsigned long long)hi << 32);
  *(unsigned long long*)((char*)buf + swz(row, colEl, strideB)) = v;
}
// pst read via the SAME type as the writes (u64): exact aliasing preserves
// write->read order without fences.
__device__ __forceinline__ s16x8 ldsRdP(const unsigned short* buf, int row, int colEl, int strideB) {
  const char* p = (const char*)buf;
  unsigned long long lo = *(const unsigned long long*)(p + swz(row, colEl, strideB));
  unsigned long long hi = *(const unsigned long long*)(p + swz(row, colEl, strideB) + 8);
  union { unsigned long long q[2]; s16x8 v; } u;
  u.q[0] = lo; u.q[1] = hi;
  return u.v;
}
__device__ __forceinline__ void ldsWr128(unsigned short* buf, int row, int colEl, int strideB, uint4 v) {
  *(uint4*)((char*)buf + swz(row, colEl, strideB)) = v;
}
__device__ __forceinline__ s16x8 u4cast(unsigned a, unsigned b, unsigned c, unsigned d) {
  union { uint4 u; s16x8 v; } cv;
  cv.u = make_uint4(a, b, c, d);
  return cv.v;
}
__device__ __forceinline__ unsigned long long ones64(int n) {
  return (n >= 64) ? ~0ULL : ((n <= 0) ? 0ULL : ((1ULL << n) - 1ULL));
}
__device__ __forceinline__ int clamp07(int v) { return v < 0 ? 0 : (v > 7 ? 7 : v); }
__device__ __forceinline__ int gidx_of(int i, int b, int nt, int nh, int nw) {
  int dt = (i >= 49) ? 1 : 0;
  int rem = i - dt * 49;
  int dh = (rem * 37) >> 8;
  int dw = rem - dh * 7;
  int t = nt * 2 + dt, h = nh * 7 + dh, w = nw * 7 + dw;
  int ts = (t + 1) & 15;
  int hs = h + 3; if (hs >= 56) hs -= 56;
  int ws2 = w + 3; if (ws2 >= 56) ws2 -= 56;
  return ((b * 16 + ts) * 56 + hs) * 56 + ws2;
}

// ---------------- weight prepack: fp32 -> bf16 fragments (exact RNE) ----------------
__global__ void prepack_weights(const float* __restrict__ wqkv,
                                const float* __restrict__ wproj,
                                unsigned short* __restrict__ dst) {
  const float QSCALE = (float)(0.17677669529663687 * 1.4426950408889634);
  int lane = threadIdx.x;
  int blk = blockIdx.x;
  if (blk < 96) {
    int ct = blk >> 2, ks = blk & 3;
    int r0 = ks * 32 + ((lane >> 4) << 3);
    int col = ct * 16 + (lane & 15);
    float scl = (ct < 8) ? QSCALE : 1.0f;
    unsigned short* d = dst + (((size_t)(ct * 4 + ks) * 64 + lane) * 8);
#pragma unroll
    for (int j = 0; j < 8; ++j) d[j] = f2bf(wqkv[(size_t)(r0 + j) * 384 + col] * scl);
  } else {
    int bb = blk - 96;
    int ct = bb >> 2, ks = bb & 3;
    int r0 = ks * 32 + ((lane >> 4) << 3);
    int col = ct * 16 + (lane & 15);
    unsigned short* d = dst + 49152 + (((size_t)(ct * 4 + ks) * 64 + lane) * 8);
#pragma unroll
    for (int j = 0; j < 8; ++j) d[j] = f2bf(wproj[(size_t)(r0 + j) * 128 + col]);
  }
}

// ---------------- fused kernel: one block per cuboid, 7 waves, ONE barrier ----------------
__global__ __launch_bounds__(NTH, 4) void fused_cuboid_attn(
    const float* __restrict__ x, const float* __restrict__ gamma,
    const float* __restrict__ beta, const float* __restrict__ bproj,
    const unsigned short* __restrict__ wfrag, float* __restrict__ out) {
  __shared__ Smem s;
  const int tid = threadIdx.x;
  const int lane = tid & 63;
  const int itw = tid >> 6;          // wave id == row-tile id (0..6)
  const int l15 = lane & 15;
  const int lg = lane >> 4;
  const int lg4 = lg * 4;
  const int lg8 = lg * 8;
  const int bid = blockIdx.x;
  const int b = bid >> 9;
  const int n = bid & 511;
  const int nt = n >> 6, nh = (n >> 3) & 7, nw = n & 7;
  // cross-lg relayout constants (Q frag and proj O frag)
  const int srcA = (2 * (lg & 1)) * 16 + l15;
  const int srcB = (2 * (lg & 1) + 1) * 16 + l15;
  const bool hiT = (lg >> 1) != 0;

  // phase 1a: issue x loads for this wave's OWN tokens (wave w owns rows
  // 16w..16w+15; 16-lane group lg handles 4 serially). Wave-own LN makes the
  // whole LN -> xf -> QKV pipeline wave-private (no barriers).
  float4 xv[4][2];
#pragma unroll
  for (int k = 0; k < 4; ++k) {
    int i = itw * 16 + lg * 4 + k;
    if (i < VOL) {
      const float* xp = x + (size_t)gidx_of(i, b, nt, nh, nw) * CH + l15 * 8;
      xv[k][0] = *(const float4*)(xp);
      xv[k][1] = *(const float4*)(xp + 4);
    }
  }

  // phase 1b: LayerNorm into bufA (own rows only)
  {
    const float4 g0 = *(const float4*)(gamma + l15 * 8);
    const float4 g1 = *(const float4*)(gamma + l15 * 8 + 4);
    const float4 be0 = *(const float4*)(beta + l15 * 8);
    const float4 be1 = *(const float4*)(beta + l15 * 8 + 4);
#pragma unroll
    for (int k = 0; k < 4; ++k) {
      int i = itw * 16 + lg * 4 + k;
      if (i < VOL) {
        float4 v0 = xv[k][0];
        float4 v1 = xv[k][1];
        float sum = v0.x + v0.y + v0.z + v0.w + v1.x + v1.y + v1.z + v1.w;
        float ssq = v0.x * v0.x + v0.y * v0.y + v0.z * v0.z + v0.w * v0.w +
                    v1.x * v1.x + v1.y * v1.y + v1.z * v1.z + v1.w * v1.w;
#pragma unroll
        for (int d = 1; d < 16; d <<= 1) {
          sum += __shfl_xor(sum, d);
          ssq += __shfl_xor(ssq, d);
        }
        float mean = sum * (1.0f / 128.0f);
        float var = ssq * (1.0f / 128.0f) - mean * mean;
        float rstd = rsqrtf(var + 1e-5f);
        uint4 pkv;
        pkv.x = pk2((v0.x - mean) * rstd * g0.x + be0.x, (v0.y - mean) * rstd * g0.y + be0.y);
        pkv.y = pk2((v0.z - mean) * rstd * g0.z + be0.z, (v0.w - mean) * rstd * g0.w + be0.w);
        pkv.z = pk2((v1.x - mean) * rstd * g1.x + be1.x, (v1.y - mean) * rstd * g1.y + be1.y);
        pkv.w = pk2((v1.z - mean) * rstd * g1.z + be1.z, (v1.w - mean) * rstd * g1.w + be1.w);
        ldsWr128(s.bufA, i, l15 * 8, 256, pkv);
      }
    }
  }
  // wave 6: zero its own pad rows 98..111 (wave-private) before its xf load
  if (itw == 6) {
    uint4 z = make_uint4(0, 0, 0, 0);
    uint4* px = (uint4*)(s.bufA + 98 * CH);
#pragma unroll
    for (int r = 0; r < 4; ++r) {
      int idx = lane + r * 64;
      if (idx < 224) px[idx] = z;
    }
  }
  asm volatile("" ::: "memory");  // order LN uint4* writes vs xf short8* reads

  // phase 2: own-row A-frags, then QKV GEMM (all writes wave-private:
  // K -> own bufA rows, V -> own vt token-cols).
  s16x8 xf[4];
#pragma unroll
  for (int ks = 0; ks < 4; ++ks) xf[ks] = ldsRd(s.bufA, itw * 16 + l15, ks * 32 + lg8, 256);
  asm volatile("" ::: "memory");

  unsigned qp[8][2];
  {
#pragma unroll
    for (int ct = 0; ct < 24; ++ct) {
      const unsigned short* wf = wfrag + ((size_t)ct * 2048 + (size_t)lane * 8);
      s16x8 wv[4];
#pragma unroll
      for (int ks = 0; ks < 4; ++ks) wv[ks] = *(const s16x8*)(wf + ks * 512);
      f32x4_t acc = {0.f, 0.f, 0.f, 0.f};
      if (ct < 16) {
#pragma unroll
        for (int ks = 0; ks < 4; ++ks)
          acc = __builtin_amdgcn_mfma_f32_16x16x32_bf16(wv[ks], xf[ks], acc, 0, 0, 0);
        if (ct < 8) {   // Q pre-scaled in prepack
          qp[ct][0] = pk2(acc[0], acc[1]);
          qp[ct][1] = pk2(acc[2], acc[3]);
        } else {
          ldsWr64(s.bufA, itw * 16 + l15, (ct - 8) * 16 + lg4, 256,
                  pk2(acc[0], acc[1]), pk2(acc[2], acc[3]));
        }
      } else {
#pragma unroll
        for (int ks = 0; ks < 4; ++ks)
          acc = __builtin_amdgcn_mfma_f32_16x16x32_bf16(xf[ks], wv[ks], acc, 0, 0, 0);
        ldsWr64(s.vt, (ct - 16) * 16 + l15, itw * 16 + lg4, 256,
                pk2(acc[0], acc[1]), pk2(acc[2], acc[3]));
      }
    }
  }
  // wave 6: zero vt token-cols 112..127 (PV ks=3 reads them x P=0) — 8 stores
  if (itw == 6) {
    uint4 z = make_uint4(0, 0, 0, 0);
#pragma unroll
    for (int r = 0; r < 2; ++r) {
      int row = lane + r * 64;
      ldsWr128(s.vt, row, 112, 256, z);
      ldsWr128(s.vt, row, 120, 256, z);
    }
  }
  __syncthreads();   // THE barrier: K + V^T complete block-wide

  // phase 3: attention, all 4 heads per wave. S^T = mfma(K, Q, C=mask).
  // Mask built CLOSED-FORM per lane (no LDS table, no atomics): cat equality
  // is separable -> mask = Tmask & Hmask & Wmask, each derived from block
  // coords. T: two fixed 49-bit halves. H: contiguous dh-range [7a,7b)
  // replicated at offsets 0/49. W: 7-bit pattern with period 7 (7|49, so
  // word k = pattern >> (32k mod 7), shifts {0,4,1,5}).
  unsigned oreg[4][4];
  {
    unsigned short* ps = s.pst[itw];
    const int q = itw * 16 + l15;
    // query category components
    int dtq = (q >= 49) ? 1 : 0;
    int remq = q - dtq * 49;
    int dhq = (remq * 37) >> 8;
    int dwq = remq - dhq * 7;
    const int tc0 = (nt < 7) ? 0 : 1;        // cat-t of dt=0 tokens
    const int tc1 = (nt < 7) ? 0 : 2;        // cat-t of dt=1 tokens
    const int tqc = dtq ? tc1 : tc0;
    const int hb1 = clamp07(49 - 7 * nh), hb2 = clamp07(53 - 7 * nh);
    const int hqc = (dhq < hb1) ? 0 : ((dhq < hb2) ? 1 : 2);
    const int wb1 = clamp07(49 - 7 * nw), wb2 = clamp07(53 - 7 * nw);
    const int wqc = (dwq < wb1) ? 0 : ((dwq < wb2) ? 1 : 2);
    // T words (bits 0..48 = dt0, bits 49..97 = dt1)
    unsigned mt0 = (tqc == tc0) ? 0xFFFFFFFFu : 0u;
    unsigned mt1 = ((tqc == tc0) ? 0x0001FFFFu : 0u) | ((tqc == tc1) ? 0xFFFE0000u : 0u);
    unsigned mt2 = (tqc == tc1) ? 0xFFFFFFFFu : 0u;
    unsigned mt3 = (tqc == tc1) ? 0x00000003u : 0u;
    // H words: dh range [ha,hbb) -> bits [7ha,7hbb) + [49+7ha,49+7hbb)
    int ha = (hqc == 0) ? 0 : ((hqc == 1) ? hb1 : hb2);
    int hbb = (hqc == 0) ? hb1 : ((hqc == 1) ? hb2 : 7);
    int s1 = 7 * ha, e1 = 7 * hbb;
    int s2 = 49 + s1, e2 = 49 + e1;
    unsigned long long hlo64 = (ones64(e1) & ~ones64(s1)) |
                               (ones64(e2 < 64 ? e2 : 64) & ~ones64(s2 < 64 ? s2 : 64));
    unsigned long long hhi64 = ones64(e2 - 64) & ~ones64(s2 - 64);
    // W words: dw range [wa,wbb) -> 7-bit pattern, period-7 replication
    int wa = (wqc == 0) ? 0 : ((wqc == 1) ? wb1 : wb2);
    int wbb = (wqc == 0) ? wb1 : ((wqc == 1) ? wb2 : 7);
    unsigned long long p7 = ((1u << wbb) - 1u) & ~((1u << wa) - 1u);
    unsigned long long rw = p7;
    rw |= rw << 7; rw |= rw << 14; rw |= rw << 28;   // periodic through bit ~62
    unsigned mwv0 = mt0 & (unsigned)hlo64 & (unsigned)rw;
    unsigned mwv1 = mt1 & (unsigned)(hlo64 >> 32) & (unsigned)(rw >> 4);
    unsigned mwv2 = mt2 & (unsigned)hhi64 & (unsigned)(rw >> 1);
    unsigned mwv3 = mt3 & (unsigned)(hhi64 >> 32) & (unsigned)(rw >> 5);
    f32x4_t cm[7];
#pragma unroll
    for (int jt = 0; jt < 7; ++jt) {
      unsigned mword = ((jt >> 1) == 0) ? mwv0 : ((jt >> 1) == 1) ? mwv1
                      : ((jt >> 1) == 2) ? mwv2 : mwv3;
#pragma unroll
      for (int r = 0; r < 4; ++r)
        cm[jt][r] = ((mword >> ((jt & 1) * 16 + lg4 + r)) & 1u) ? 0.f : MASKNEG;
    }
#pragma unroll
    for (int hh = 0; hh < 4; ++hh) {
      // qa fragment from Q registers via cross-lg shuffles
      unsigned a0 = __shfl(qp[2 * hh][0], srcA), b0 = __shfl(qp[2 * hh + 1][0], srcA);
      unsigned a1 = __shfl(qp[2 * hh][1], srcA), b1 = __shfl(qp[2 * hh + 1][1], srcA);
      unsigned a2 = __shfl(qp[2 * hh][0], srcB), b2 = __shfl(qp[2 * hh + 1][0], srcB);
      unsigned a3 = __shfl(qp[2 * hh][1], srcB), b3 = __shfl(qp[2 * hh + 1][1], srcB);
      s16x8 qa = u4cast(hiT ? b0 : a0, hiT ? b1 : a1, hiT ? b2 : a2, hiT ? b3 : a3);
      f32x4_t sc[7];
#pragma unroll
      for (int jt = 0; jt < 7; ++jt) {
        s16x8 kb = ldsRd(s.bufA, jt * 16 + l15, hh * 32 + lg8, 256);
        sc[jt] = __builtin_amdgcn_mfma_f32_16x16x32_bf16(kb, qa, cm[jt], 0, 0, 0);
      }
      // p = exp2(s) (log2 domain; scale folded into prepacked Wq); row sum
      float s0 = 0.f, s1f = 0.f, s2f = 0.f, s3 = 0.f;
#pragma unroll
      for (int jt = 0; jt < 7; ++jt) {
        float p0 = exp2f(sc[jt][0]);
        float p1 = exp2f(sc[jt][1]);
        float p2 = exp2f(sc[jt][2]);
        float p3 = exp2f(sc[jt][3]);
        sc[jt][0] = p0; sc[jt][1] = p1; sc[jt][2] = p2; sc[jt][3] = p3;
        s0 += p0; s1f += p1; s2f += p2; s3 += p3;
      }
      float ssum = (s0 + s1f) + (s2f + s3);
      ssum += __shfl_xor(ssum, 16);
      ssum += __shfl_xor(ssum, 32);
      float rinv = 1.0f / ssum;
      f32x4_t o0 = {0.f, 0.f, 0.f, 0.f}, o1 = {0.f, 0.f, 0.f, 0.f};
      // half A: keys 0..63 (jt 0..3)
#pragma unroll
      for (int jt = 0; jt < 4; ++jt)
        ldsWr64(ps, l15, jt * 16 + lg4, 128, pk2(sc[jt][0], sc[jt][1]), pk2(sc[jt][2], sc[jt][3]));
#pragma unroll
      for (int ks = 0; ks < 2; ++ks) {
        s16x8 pa = ldsRdP(ps, l15, ks * 32 + lg8, 128);
        s16x8 v0 = ldsRd(s.vt, hh * 32 + l15, ks * 32 + lg8, 256);
        s16x8 v1 = ldsRd(s.vt, hh * 32 + 16 + l15, ks * 32 + lg8, 256);
        o0 = __builtin_amdgcn_mfma_f32_16x16x32_bf16(v0, pa, o0, 0, 0, 0);
        o1 = __builtin_amdgcn_mfma_f32_16x16x32_bf16(v1, pa, o1, 0, 0, 0);
      }
      // half B: keys 64..127 (jt 4..6 + zero pad)
#pragma unroll
      for (int jt = 4; jt < 7; ++jt)
        ldsWr64(ps, l15, (jt - 4) * 16 + lg4, 128, pk2(sc[jt][0], sc[jt][1]), pk2(sc[jt][2], sc[jt][3]));
      ldsWr64(ps, l15, 48 + lg4, 128, 0u, 0u);
#pragma unroll
      for (int ks = 0; ks < 2; ++ks) {
        s16x8 pa = ldsRdP(ps, l15, ks * 32 + lg8, 128);
        s16x8 v0 = ldsRd(s.vt, hh * 32 + l15, (2 + ks) * 32 + lg8, 256);
        s16x8 v1 = ldsRd(s.vt, hh * 32 + 16 + l15, (2 + ks) * 32 + lg8, 256);
        o0 = __builtin_amdgcn_mfma_f32_16x16x32_bf16(v0, pa, o0, 0, 0, 0);
        o1 = __builtin_amdgcn_mfma_f32_16x16x32_bf16(v1, pa, o1, 0, 0, 0);
      }
      oreg[hh][0] = pk2(o0[0] * rinv, o0[1] * rinv);
      oreg[hh][1] = pk2(o0[2] * rinv, o0[3] * rinv);
      oreg[hh][2] = pk2(o1[0] * rinv, o1[1] * rinv);
      oreg[hh][3] = pk2(o1[2] * rinv, o1[3] * rinv);
    }
  }

  // phase 4: proj A-frags straight from oreg via cross-lg shuffles (no LDS,
  // no barriers; gidx closed-form per lane).
  {
    s16x8 of[4];
#pragma unroll
    for (int hh = 0; hh < 4; ++hh) {
      unsigned a0 = __shfl(oreg[hh][0], srcA), a2 = __shfl(oreg[hh][2], srcA);
      unsigned a1 = __shfl(oreg[hh][1], srcA), a3 = __shfl(oreg[hh][3], srcA);
      unsigned c0 = __shfl(oreg[hh][0], srcB), c2 = __shfl(oreg[hh][2], srcB);
      unsigned c1 = __shfl(oreg[hh][1], srcB), c3 = __shfl(oreg[hh][3], srcB);
      of[hh] = u4cast(hiT ? a2 : a0, hiT ? a3 : a1, hiT ? c2 : c0, hiT ? c3 : c1);
    }
    const unsigned short* wp = wfrag + 49152;
    const int row = itw * 16 + l15;
    const bool valid = row < VOL;
    const size_t gbase = valid ? (size_t)gidx_of(row, b, nt, nh, nw) * CH : 0;
#pragma unroll
    for (int ct = 0; ct < 8; ++ct) {
      const unsigned short* wf = wp + ((size_t)ct * 2048 + (size_t)lane * 8);
      float4 b4 = *(const float4*)(bproj + ct * 16 + lg4);
      f32x4_t acc = {b4.x, b4.y, b4.z, b4.w};
#pragma unroll
      for (int ks = 0; ks < 4; ++ks) {
        s16x8 wv = *(const s16x8*)(wf + ks * 512);
        acc = __builtin_amdgcn_mfma_f32_16x16x32_bf16(wv, of[ks], acc, 0, 0, 0);
      }
      if (valid) {
        float4 res;
        res.x = acc[0]; res.y = acc[1]; res.z = acc[2]; res.w = acc[3];
        *(float4*)(out + gbase + ct * 16 + lg4) = res;
      }
    }
  }
}

extern "C" void kernel_launch(void* const* d_in, const int* in_sizes, int n_in,
                              void* d_out, int out_size, void* d_ws, size_t ws_size,
                              hipStream_t stream) {
  const float* x = (const float*)d_in[0];
  const float* gamma = (const float*)d_in[1];
  const float* beta = (const float*)d_in[2];
  const float* wqkv = (const float*)d_in[3];
  const float* wproj = (const float*)d_in[4];
  const float* bproj = (const float*)d_in[5];
  float* out = (float*)d_out;
  unsigned short* wsf = (unsigned short*)d_ws;
  (void)in_sizes; (void)n_in; (void)out_size; (void)ws_size;

  prepack_weights<<<128, 64, 0, stream>>>(wqkv, wproj, wsf);
  fused_cuboid_attn<<<1024, NTH, 0, stream>>>(x, gamma, beta, bproj, wsf, out);
}